// Round 1
// baseline (374.206 us; speedup 1.0000x reference)
//
#include <hip/hip_runtime.h>

#define DD 256
#define BB 512

// workspace layout (float offsets)
#define OFF_RS   0          // 512*256 row sums
#define OFF_CSP  131072     // 2048*256 col-sum partials (4 per batch)
#define OFF_HFC  655360     // 4 fc1 pre-activations
#define OFF_SBP  655368     // 10 sorted breakpoints
#define OFF_TABA 655384     // 11*9 A table
#define OFF_TABB 655488     // 11*9 B table
// total ~2.63 MB of d_ws

__device__ __forceinline__ float wave_red(float v) {
#pragma unroll
  for (int off = 32; off > 0; off >>= 1) v += __shfl_down(v, off, 64);
  return v;
}

// ---- build piecewise-linear tables: q_t(e) = A[s][t]*e + B[s][t] ----
__global__ void ktab_kernel(const float* __restrict__ w1, const float* __restrict__ b1,
                            const float* __restrict__ w2, float* __restrict__ ws) {
  int tid = threadIdx.x;
  float w1v[10], b1v[10], bp[10];
  int rank[10];
#pragma unroll
  for (int c = 0; c < 10; ++c) { w1v[c] = w1[c]; b1v[c] = b1[c]; bp[c] = -b1v[c] / w1v[c]; }
#pragma unroll
  for (int c = 0; c < 10; ++c) {
    int r = 0;
#pragma unroll
    for (int k = 0; k < 10; ++k)
      r += (bp[k] < bp[c] || (bp[k] == bp[c] && k < c)) ? 1 : 0;
    rank[c] = r;
  }
  if (tid < 10) ws[OFF_SBP + rank[tid]] = bp[tid];
  if (tid < 11) {
    int s = tid;  // interval: #breakpoints < e
    for (int t = 0; t < 9; ++t) {
      float A = 0.f, Bv = 0.f;
      for (int c = 0; c < 10; ++c) {
        bool act = (w1v[c] > 0.f) ? (rank[c] < s)
                 : ((w1v[c] < 0.f) ? (rank[c] >= s) : (b1v[c] > 0.f));
        if (act) { A += w1v[c] * w2[c * 9 + t]; Bv += b1v[c] * w2[c * 9 + t]; }
      }
      ws[OFF_TABA + s * 9 + t] = A;
      ws[OFF_TABB + s * 9 + t] = Bv;
    }
  }
}

// ---- K1: row sums + col-sum partials of x [512,256,256]; one float4/lane = one row ----
__global__ __launch_bounds__(256) void sum_kernel(const float* __restrict__ x,
                                                  float* __restrict__ ws) {
  const int bq = blockIdx.x;         // 2048 blocks: 4 per batch
  const int b = bq >> 2;
  const int q = bq & 3;
  const int tid = threadIdx.x;
  const int lane = tid & 63;
  const int wv = tid >> 6;
  __shared__ float csl[4][DD];
  float4 cacc = make_float4(0.f, 0.f, 0.f, 0.f);
  const int rowbase = q * 64 + wv * 16;
#pragma unroll 4
  for (int r = 0; r < 16; ++r) {
    const int i = rowbase + r;
    const float4* px = (const float4*)(x + ((size_t)b << 16) + ((size_t)i << 8));
    float4 val = px[lane];
    cacc.x += val.x; cacc.y += val.y; cacc.z += val.z; cacc.w += val.w;
    float rsum = (val.x + val.y) + (val.z + val.w);
    rsum = wave_red(rsum);
    if (lane == 0) ws[OFF_RS + b * DD + i] = rsum;
  }
  ((float4*)csl[wv])[lane] = cacc;
  __syncthreads();
  ws[OFF_CSP + bq * DD + tid] = csl[0][tid] + csl[1][tid] + csl[2][tid] + csl[3][tid];
  if (bq == 0 && tid < 4) ws[OFF_HFC + tid] = 0.f;  // zero fc1 accumulators (ws is poisoned)
}

// ---- K2: fused conv3x3(relu(e*w1+b1)*tril)+bias+relu + row/col reduce + fc1 partial ----
__global__ __launch_bounds__(256) void conv_kernel(const float* __restrict__ b2p,
                                                   const float* __restrict__ fc1w,
                                                   float* __restrict__ ws) {
  const int b = blockIdx.x;          // one block per batch image
  const int tid = threadIdx.x;       // thread = output column j
  const int lane = tid & 63;
  const int wv = tid >> 6;
  const int j = tid;

  __shared__ float rs_s[DD];
  __shared__ float cs_s[DD];
  __shared__ float tabA_s[99];
  __shared__ float tabB_s[99];
  __shared__ float vrow_s[DD * 4];
  __shared__ float red_s[16];

  rs_s[tid] = ws[OFF_RS + b * DD + tid];
  const float* csp = ws + OFF_CSP + (b * 4) * DD + tid;
  cs_s[tid] = csp[0] + csp[DD] + csp[2 * DD] + csp[3 * DD];
  if (tid < 99) { tabA_s[tid] = ws[OFF_TABA + tid]; tabB_s[tid] = ws[OFF_TABB + tid]; }
  __syncthreads();

  float sbpv[10];
#pragma unroll
  for (int k = 0; k < 10; ++k) sbpv[k] = ws[OFF_SBP + k];
  const float lo = sbpv[0], hi = sbpv[9];
  const float b2v = b2p[0];

  // fast-path tables (outer intervals s=0 / s=10) live in registers
  float A0r[9], B0r[9], A1r[9], B1r[9];
#pragma unroll
  for (int t = 0; t < 9; ++t) {
    A0r[t] = tabA_s[t];      B0r[t] = tabB_s[t];
    A1r[t] = tabA_s[90 + t]; B1r[t] = tabB_s[90 + t];
  }

  float csr[3], vf[3];
  csr[0] = (j >= 1) ? cs_s[j - 1] : 0.f;
  csr[1] = cs_s[j];
  csr[2] = (j < DD - 1) ? cs_s[j + 1] : 0.f;
  vf[0] = (j >= 1) ? 1.f : 0.f;
  vf[1] = 1.f;
  vf[2] = (j < DD - 1) ? 1.f : 0.f;

  float P = 0.f, Q = 0.f, vcol = 0.f;  // vertical rolling pipeline + column-sum acc

  for (int i = 0; i < DD; ++i) {       // i = input row
    const float rsv = rs_s[i];
    float R0 = 0.f, R1 = 0.f, R2 = 0.f;
    if (j - 1 <= i) {                  // else: all 3 input cols tril-masked -> R=0
#pragma unroll
      for (int kc = 0; kc < 3; ++kc) {
        float e = rsv + csr[kc];
        bool pos = e > hi;
        float a0 = pos ? A1r[kc]     : A0r[kc];
        float a1 = pos ? A1r[3 + kc] : A0r[3 + kc];
        float a2 = pos ? A1r[6 + kc] : A0r[6 + kc];
        float g0 = pos ? B1r[kc]     : B0r[kc];
        float g1 = pos ? B1r[3 + kc] : B0r[3 + kc];
        float g2 = pos ? B1r[6 + kc] : B0r[6 + kc];
        if (e >= lo && e <= hi) {      // rare middle zone: exact interval via LDS table
          int s = 0;
#pragma unroll
          for (int k = 0; k < 10; ++k) s += (sbpv[k] < e) ? 1 : 0;
          a0 = tabA_s[s * 9 + kc];     g0 = tabB_s[s * 9 + kc];
          a1 = tabA_s[s * 9 + 3 + kc]; g1 = tabB_s[s * 9 + 3 + kc];
          a2 = tabA_s[s * 9 + 6 + kc]; g2 = tabB_s[s * 9 + 6 + kc];
        }
        float m = ((j - 1 + kc) <= i) ? vf[kc] : 0.f;  // tril + horizontal padding
        R0 = fmaf(m, fmaf(a0, e, g0), R0);
        R1 = fmaf(m, fmaf(a1, e, g1), R1);
        R2 = fmaf(m, fmaf(a2, e, g2), R2);
      }
    }
    if (i > 0) {                       // finalize output row i-1 = P + R2(i)
      float y = fmaxf(P + R2 + b2v, 0.f);
      vcol += y;
      float t = wave_red(y);
      if (lane == 0) vrow_s[(i - 1) * 4 + wv] = t;
    }
    P = Q + R1;
    Q = R0;
  }
  {                                    // flush output row 255 (R2 from row 256 = 0)
    float y = fmaxf(P + b2v, 0.f);
    vcol += y;
    float t = wave_red(y);
    if (lane == 0) vrow_s[(DD - 1) * 4 + wv] = t;
  }
  __syncthreads();

  float vr = vrow_s[tid * 4 + 0] + vrow_s[tid * 4 + 1] +
             vrow_s[tid * 4 + 2] + vrow_s[tid * 4 + 3];
  float v = vr + vcol;                 // v[b, tid] = rowsum + colsum

  // fc1 partial: flat[n]=v[b,tid], n = b*256+tid; block-reduce 4 dots, 4 atomics/block
  const int nidx = b * DD + tid;
  float p0 = fc1w[0 * (BB * DD) + nidx] * v;
  float p1 = fc1w[1 * (BB * DD) + nidx] * v;
  float p2 = fc1w[2 * (BB * DD) + nidx] * v;
  float p3 = fc1w[3 * (BB * DD) + nidx] * v;
  p0 = wave_red(p0); p1 = wave_red(p1); p2 = wave_red(p2); p3 = wave_red(p3);
  if (lane == 0) {
    red_s[wv * 4 + 0] = p0; red_s[wv * 4 + 1] = p1;
    red_s[wv * 4 + 2] = p2; red_s[wv * 4 + 3] = p3;
  }
  __syncthreads();
  if (tid < 4) {
    float s = red_s[tid] + red_s[4 + tid] + red_s[8 + tid] + red_s[12 + tid];
    atomicAdd(&ws[OFF_HFC + tid], s);
  }
}

// ---- K3: relu(fc1) -> fc2 -> 2 outputs ----
__global__ void fc_kernel(const float* __restrict__ fc1b, const float* __restrict__ fc2w,
                          const float* __restrict__ fc2b, const float* __restrict__ ws,
                          float* __restrict__ out) {
  if (threadIdx.x == 0 && blockIdx.x == 0) {
    float o0 = fc2b[0], o1 = fc2b[1];
#pragma unroll
    for (int k = 0; k < 4; ++k) {
      float h = fmaxf(ws[OFF_HFC + k] + fc1b[k], 0.f);
      o0 += fc2w[k] * h;
      o1 += fc2w[4 + k] * h;
    }
    out[0] = o0; out[1] = o1;
  }
}

extern "C" void kernel_launch(void* const* d_in, const int* in_sizes, int n_in,
                              void* d_out, int out_size, void* d_ws, size_t ws_size,
                              hipStream_t stream) {
  const float* x    = (const float*)d_in[0];
  const float* w1   = (const float*)d_in[1];
  const float* b1   = (const float*)d_in[2];
  const float* w2   = (const float*)d_in[3];
  const float* b2   = (const float*)d_in[4];
  const float* fc1w = (const float*)d_in[5];
  const float* fc1b = (const float*)d_in[6];
  const float* fc2w = (const float*)d_in[7];
  const float* fc2b = (const float*)d_in[8];
  float* out = (float*)d_out;
  float* ws  = (float*)d_ws;

  hipLaunchKernelGGL(ktab_kernel, dim3(1), dim3(64), 0, stream, w1, b1, w2, ws);
  hipLaunchKernelGGL(sum_kernel,  dim3(2048), dim3(256), 0, stream, x, ws);
  hipLaunchKernelGGL(conv_kernel, dim3(512), dim3(256), 0, stream, b2, fc1w, ws);
  hipLaunchKernelGGL(fc_kernel,   dim3(1), dim3(64), 0, stream, fc1b, fc2w, fc2b, ws, out);
}

// Round 2
// 325.348 us; speedup vs baseline: 1.1502x; 1.1502x over previous
//
#include <hip/hip_runtime.h>

#define DD 256
#define BB 512

// workspace layout (float offsets)
#define OFF_RS   0          // 512*256 row sums
#define OFF_CSP  131072     // 2048*256 col-sum partials (4 per batch)
#define OFF_HFC  655360     // 4 fc1 pre-activations
#define OFF_SBP  655368     // 10 sorted breakpoints
#define OFF_TABA 655384     // 11*9 A table
#define OFF_TABB 655488     // 11*9 B table

__device__ __forceinline__ float wave_red(float v) {
#pragma unroll
  for (int off = 32; off > 0; off >>= 1) v += __shfl_down(v, off, 64);
  return v;
}

// ---- build piecewise-linear tables: q_t(e) = A[s][t]*e + B[s][t] ----
__global__ void ktab_kernel(const float* __restrict__ w1, const float* __restrict__ b1,
                            const float* __restrict__ w2, float* __restrict__ ws) {
  int tid = threadIdx.x;
  float w1v[10], b1v[10], bp[10];
  int rank[10];
#pragma unroll
  for (int c = 0; c < 10; ++c) { w1v[c] = w1[c]; b1v[c] = b1[c]; bp[c] = -b1v[c] / w1v[c]; }
#pragma unroll
  for (int c = 0; c < 10; ++c) {
    int r = 0;
#pragma unroll
    for (int k = 0; k < 10; ++k)
      r += (bp[k] < bp[c] || (bp[k] == bp[c] && k < c)) ? 1 : 0;
    rank[c] = r;
  }
  if (tid < 10) ws[OFF_SBP + rank[tid]] = bp[tid];
  if (tid < 11) {
    int s = tid;  // interval: #breakpoints < e
    for (int t = 0; t < 9; ++t) {
      float A = 0.f, Bv = 0.f;
      for (int c = 0; c < 10; ++c) {
        bool act = (w1v[c] > 0.f) ? (rank[c] < s)
                 : ((w1v[c] < 0.f) ? (rank[c] >= s) : (b1v[c] > 0.f));
        if (act) { A += w1v[c] * w2[c * 9 + t]; Bv += b1v[c] * w2[c * 9 + t]; }
      }
      ws[OFF_TABA + s * 9 + t] = A;
      ws[OFF_TABB + s * 9 + t] = Bv;
    }
  }
}

// ---- K1: row sums + col-sum partials; no shuffles, LDS-transpose row reduce ----
__global__ __launch_bounds__(256) void sum_kernel(const float* __restrict__ x,
                                                  float* __restrict__ ws) {
  const int bq = blockIdx.x;         // 2048 blocks: 4 per batch (64 rows each)
  const int b = bq >> 2;
  const int q = bq & 3;
  const int tid = threadIdx.x;
  const int lane = tid & 63;
  const int wv = tid >> 6;
  __shared__ float rowp[64][65];     // per-lane row partials (padded: conflict-free)
  __shared__ float csl[4][DD];
  __shared__ float segp[4][64];
  float4 cacc = make_float4(0.f, 0.f, 0.f, 0.f);
  const float4* px = (const float4*)(x + ((size_t)b << 16) + ((size_t)(q * 64 + wv * 16) << 8));
#pragma unroll
  for (int r = 0; r < 16; ++r) {     // 16 independent loads -> full MLP
    float4 val = px[r * 64 + lane];
    cacc.x += val.x; cacc.y += val.y; cacc.z += val.z; cacc.w += val.w;
    rowp[wv * 16 + r][lane] = (val.x + val.y) + (val.z + val.w);
  }
  ((float4*)csl[wv])[lane] = cacc;
  __syncthreads();
  {                                  // 4 threads per row sum 16 partials each
    const int row = tid & 63, seg = tid >> 6;
    const float* rp = rowp[row] + seg * 16;
    float s = 0.f;
#pragma unroll
    for (int k = 0; k < 16; ++k) s += rp[k];
    segp[seg][row] = s;
  }
  __syncthreads();
  if (tid < 64)
    ws[OFF_RS + b * DD + q * 64 + tid] =
        (segp[0][tid] + segp[1][tid]) + (segp[2][tid] + segp[3][tid]);
  ws[OFF_CSP + bq * DD + tid] =
      (csl[0][tid] + csl[1][tid]) + (csl[2][tid] + csl[3][tid]);
  if (bq == 0 && tid < 4) ws[OFF_HFC + tid] = 0.f;  // zero fc1 accumulators
}

// ---- K2: fused conv3x3(relu(e*w1+b1)*tril)+bias+relu + direct fc1 accumulation ----
// hfc[k] = sum_{b,i,j} y[b,i,j]*(Wk[b,i]+Wk[b,j]) -- no per-row reduction needed.
__global__ __launch_bounds__(256) void conv_kernel(const float* __restrict__ b2p,
                                                   const float* __restrict__ fc1w,
                                                   float* __restrict__ ws) {
  const int blk = blockIdx.x;        // 2048 blocks: 4 row-chunks per image
  const int b = blk >> 2;
  const int chunk = blk & 3;
  const int r0 = chunk * 64, r1 = r0 + 64;
  const int tid = threadIdx.x;       // thread = output column j
  const int lane = tid & 63;
  const int wv = tid >> 6;
  const int j = tid;

  __shared__ float rs_s[DD];
  __shared__ float cs_s[DD];
  __shared__ float tabA_s[99];
  __shared__ float tabB_s[99];
  __shared__ float sbp_s[10];
  __shared__ float wk_s[64][4];      // Wk[b, r0..r1-1], float4 per row
  __shared__ float red_s[16];

  rs_s[tid] = ws[OFF_RS + b * DD + tid];
  const float* csp = ws + OFF_CSP + (b * 4) * DD + tid;
  cs_s[tid] = (csp[0] + csp[DD]) + (csp[2 * DD] + csp[3 * DD]);
  if (tid < 99) { tabA_s[tid] = ws[OFF_TABA + tid]; tabB_s[tid] = ws[OFF_TABB + tid]; }
  if (tid < 10) sbp_s[tid] = ws[OFF_SBP + tid];
  if (tid < 64) {
    const int r = r0 + tid;
#pragma unroll
    for (int k = 0; k < 4; ++k) wk_s[tid][k] = fc1w[k * (BB * DD) + b * DD + r];
  }
  __syncthreads();

  const float lo = sbp_s[0], hi = sbp_s[9];
  const float b2v = b2p[0];

  // fast-path tables (outer intervals s=0 / s=10) in registers
  float A0r[9], B0r[9], A1r[9], B1r[9];
#pragma unroll
  for (int t = 0; t < 9; ++t) {
    A0r[t] = tabA_s[t];      B0r[t] = tabB_s[t];
    A1r[t] = tabA_s[90 + t]; B1r[t] = tabB_s[90 + t];
  }

  float csr[3], vf[3];
  csr[0] = (j >= 1) ? cs_s[j - 1] : 0.f;
  csr[1] = cs_s[j];
  csr[2] = (j < DD - 1) ? cs_s[j + 1] : 0.f;
  vf[0] = (j >= 1) ? 1.f : 0.f;
  vf[1] = 1.f;
  vf[2] = (j < DD - 1) ? 1.f : 0.f;

  const int istart = (r0 == 0) ? 0 : r0 - 1;
  const int iend = (r1 == DD) ? DD - 1 : r1;

  float P = 0.f, Q = 0.f, vcol = 0.f;
  float acc0 = 0.f, acc1 = 0.f, acc2 = 0.f, acc3 = 0.f;

  for (int i = istart; i <= iend; ++i) {
    const float rsv = rs_s[i];
    float R0 = 0.f, R1 = 0.f, R2 = 0.f;
    if (j - 1 <= i) {                // else: all 3 input cols tril-masked -> R=0
#pragma unroll
      for (int kc = 0; kc < 3; ++kc) {
        float e = rsv + csr[kc];
        bool pos = e > hi;
        float a0 = pos ? A1r[kc]     : A0r[kc];
        float a1 = pos ? A1r[3 + kc] : A0r[3 + kc];
        float a2 = pos ? A1r[6 + kc] : A0r[6 + kc];
        float g0 = pos ? B1r[kc]     : B0r[kc];
        float g1 = pos ? B1r[3 + kc] : B0r[3 + kc];
        float g2 = pos ? B1r[6 + kc] : B0r[6 + kc];
        if (e >= lo && e <= hi) {    // rare middle zone: exact interval via LDS
          int s = 0;
#pragma unroll
          for (int k = 0; k < 10; ++k) s += (sbp_s[k] < e) ? 1 : 0;
          a0 = tabA_s[s * 9 + kc];     g0 = tabB_s[s * 9 + kc];
          a1 = tabA_s[s * 9 + 3 + kc]; g1 = tabB_s[s * 9 + 3 + kc];
          a2 = tabA_s[s * 9 + 6 + kc]; g2 = tabB_s[s * 9 + 6 + kc];
        }
        float m = ((j - 1 + kc) <= i) ? vf[kc] : 0.f;  // tril + horiz padding
        R0 = fmaf(m, fmaf(a0, e, g0), R0);
        R1 = fmaf(m, fmaf(a1, e, g1), R1);
        R2 = fmaf(m, fmaf(a2, e, g2), R2);
      }
    }
    if (i >= r0 + 1) {               // finalize output row i-1
      float y = fmaxf(P + R2 + b2v, 0.f);
      vcol += y;
      const float4 wkv = *(const float4*)wk_s[i - 1 - r0];  // LDS broadcast
      acc0 = fmaf(y, wkv.x, acc0);
      acc1 = fmaf(y, wkv.y, acc1);
      acc2 = fmaf(y, wkv.z, acc2);
      acc3 = fmaf(y, wkv.w, acc3);
    }
    P = Q + R1;
    Q = R0;
  }
  if (r1 == DD) {                    // flush output row 255 (R2 from row 256 = 0)
    float y = fmaxf(P + b2v, 0.f);
    vcol += y;
    const float4 wkv = *(const float4*)wk_s[63];
    acc0 = fmaf(y, wkv.x, acc0);
    acc1 = fmaf(y, wkv.y, acc1);
    acc2 = fmaf(y, wkv.z, acc2);
    acc3 = fmaf(y, wkv.w, acc3);
  }

  // column-sum term: vcol * Wk[b, j]
  const int nidx = b * DD + j;
  acc0 = fmaf(vcol, fc1w[0 * (BB * DD) + nidx], acc0);
  acc1 = fmaf(vcol, fc1w[1 * (BB * DD) + nidx], acc1);
  acc2 = fmaf(vcol, fc1w[2 * (BB * DD) + nidx], acc2);
  acc3 = fmaf(vcol, fc1w[3 * (BB * DD) + nidx], acc3);

  acc0 = wave_red(acc0); acc1 = wave_red(acc1);
  acc2 = wave_red(acc2); acc3 = wave_red(acc3);
  if (lane == 0) {
    red_s[wv * 4 + 0] = acc0; red_s[wv * 4 + 1] = acc1;
    red_s[wv * 4 + 2] = acc2; red_s[wv * 4 + 3] = acc3;
  }
  __syncthreads();
  if (tid < 4) {
    float s = (red_s[tid] + red_s[4 + tid]) + (red_s[8 + tid] + red_s[12 + tid]);
    atomicAdd(&ws[OFF_HFC + tid], s);
  }
}

// ---- K3: relu(fc1) -> fc2 -> 2 outputs ----
__global__ void fc_kernel(const float* __restrict__ fc1b, const float* __restrict__ fc2w,
                          const float* __restrict__ fc2b, const float* __restrict__ ws,
                          float* __restrict__ out) {
  if (threadIdx.x == 0 && blockIdx.x == 0) {
    float o0 = fc2b[0], o1 = fc2b[1];
#pragma unroll
    for (int k = 0; k < 4; ++k) {
      float h = fmaxf(ws[OFF_HFC + k] + fc1b[k], 0.f);
      o0 += fc2w[k] * h;
      o1 += fc2w[4 + k] * h;
    }
    out[0] = o0; out[1] = o1;
  }
}

extern "C" void kernel_launch(void* const* d_in, const int* in_sizes, int n_in,
                              void* d_out, int out_size, void* d_ws, size_t ws_size,
                              hipStream_t stream) {
  const float* x    = (const float*)d_in[0];
  const float* w1   = (const float*)d_in[1];
  const float* b1   = (const float*)d_in[2];
  const float* w2   = (const float*)d_in[3];
  const float* b2   = (const float*)d_in[4];
  const float* fc1w = (const float*)d_in[5];
  const float* fc1b = (const float*)d_in[6];
  const float* fc2w = (const float*)d_in[7];
  const float* fc2b = (const float*)d_in[8];
  float* out = (float*)d_out;
  float* ws  = (float*)d_ws;

  hipLaunchKernelGGL(ktab_kernel, dim3(1), dim3(64), 0, stream, w1, b1, w2, ws);
  hipLaunchKernelGGL(sum_kernel,  dim3(2048), dim3(256), 0, stream, x, ws);
  hipLaunchKernelGGL(conv_kernel, dim3(2048), dim3(256), 0, stream, b2, fc1w, ws);
  hipLaunchKernelGGL(fc_kernel,   dim3(1), dim3(64), 0, stream, fc1b, fc2w, fc2b, ws, out);
}